// Round 7
// baseline (145.840 us; speedup 1.0000x reference)
//
#include <hip/hip_runtime.h>

// N=65536, P=512, D=256, fp32 in, fp32 scalar out
#define NTOT 65536
#define PTOT 512
#define DTOT 256
#define BM   64                  // rows per block
#define BK   32                  // k-chunk
#define NK   (DTOT / BK)         // 8
#define GRID_MAIN (NTOT / BM)    // 1024
#define EPSQ 1e-12f

typedef _Float16 f16x8 __attribute__((ext_vector_type(8)));
typedef _Float16 f16x4 __attribute__((ext_vector_type(4)));
typedef float    f32x4 __attribute__((ext_vector_type(4)));

// ---- ws layout (bytes) ----
#define WS_P2      262144            // 512 f32
#define WS_COLPART 264192            // 512 * 1024 f32, TRANSPOSED: [p][bid]
#define WS_ROWPART 2361344           // 1024 f32 (per-block sum of sqrt(row sq-min))
#define WS_FMINSQ  2365440           // 512 f32 (global col sq-mins)

__device__ __forceinline__ f16x8 cvt8(const float4 a, const float4 b, float& zsq) {
  f16x8 h;
  h[0] = (_Float16)a.x; h[1] = (_Float16)a.y; h[2] = (_Float16)a.z; h[3] = (_Float16)a.w;
  h[4] = (_Float16)b.x; h[5] = (_Float16)b.y; h[6] = (_Float16)b.z; h[7] = (_Float16)b.w;
#pragma unroll
  for (int i = 0; i < 8; ++i) { float f = (float)h[i]; zsq = fmaf(f, f, zsq); }
  return h;
}

// ---------------- pre-pass: protos fp32 -> fp16 + p2 ----------------
__global__ __launch_bounds__(64) void proto_prep_k(const float* __restrict__ protos,
                                                   _Float16* __restrict__ protosH,
                                                   float* __restrict__ p2) {
  const int p = blockIdx.x;   // 512 blocks
  const int l = threadIdx.x;  // 64 threads; 4 floats each
  const float4 v = *reinterpret_cast<const float4*>(protos + (size_t)p * DTOT + l * 4);
  f16x4 h;
  h[0] = (_Float16)v.x; h[1] = (_Float16)v.y; h[2] = (_Float16)v.z; h[3] = (_Float16)v.w;
  *reinterpret_cast<f16x4*>(protosH + (size_t)p * DTOT + l * 4) = h;
  float s = 0.f;
#pragma unroll
  for (int i = 0; i < 4; ++i) { float f = (float)h[i]; s = fmaf(f, f, s); }
#pragma unroll
  for (int m = 1; m < 64; m <<= 1) s += __shfl_xor(s, m, 64);
  if (l == 0) p2[p] = s;
}

// ---------------- main: 64 rows x 512 cols per block, 4 waves ----------------
// B (protos fp16, 256 KB, L2-resident) loaded DIRECTLY into registers — no LDS,
// no global_load_lds, so the per-kstep barrier waits only on the 4 KB z ds_write
// (raw s_barrier + lgkmcnt(0); no vmcnt drain). B k+1 issued after MFMA cluster
// stays in flight ACROSS the barrier. Occupancy is register-capped (acc=128 AGPR
// -> 2 waves/SIMD); this attacks the per-kstep exposed latency instead.
__global__ __launch_bounds__(256, 2) void pdist_main_k(const float* __restrict__ z,
                                                       const _Float16* __restrict__ protosH,
                                                       const float* __restrict__ p2g,
                                                       float* __restrict__ colpart,
                                                       float* __restrict__ rowpart) {
  __shared__ _Float16 Zlds[2][BM * BK];     // 8 KB
  __shared__ float zsqs[BM];                // 256 B
  __shared__ float rowmin_s[4][BM];         // 1 KB

  const int t    = threadIdx.x;
  const int lane = t & 63;
  const int wid  = t >> 6;   // 0..3 : col strip (128 cols each)
  const int bid  = blockIdx.x;

  const int fr = lane & 15;  // fragment free index
  const int fg = lane >> 4;  // k-group

  // z staging geometry (reg -> cvt -> LDS)
  const int srow = t >> 2;   // 0..63
  const int sg   = t & 3;    // 8-float chunk within 32-float k-chunk
  const float* zsrc = z + (size_t)(bid * BM + srow) * DTOT + sg * 8;

  // per-lane B fragment base: proto row (wid*128 + fr), k-offset fg*8 (f16x8 units)
  const f16x8* pB = reinterpret_cast<const f16x8*>(protosH) +
                    ((size_t)(wid * 128 + fr) * (DTOT / 8) + fg);
  // fragment (cf, kb) at pB[cf*512 + kb*4]   (cf*16 rows * 32 units/row; kb*32 elem /8)

  float zsq = 0.f;

  f32x4 acc[4][8];
#pragma unroll
  for (int a = 0; a < 4; ++a)
#pragma unroll
    for (int b = 0; b < 8; ++b) acc[a][b] = (f32x4)0.f;

  f16x8 bfr[8];

  // prologue: z k0 -> LDS buf0; B k0 -> regs
  {
    float4 va = *reinterpret_cast<const float4*>(zsrc);
    float4 vb = *reinterpret_cast<const float4*>(zsrc + 4);
#pragma unroll
    for (int cf = 0; cf < 8; ++cf) bfr[cf] = pB[cf * 512];
    f16x8 h = cvt8(va, vb, zsq);
    *reinterpret_cast<f16x8*>(&Zlds[0][srow * BK + sg * 8]) = h;
  }
  __syncthreads();  // once; draining prologue B loads here is fine

#pragma unroll
  for (int kb = 0; kb < NK; ++kb) {
    const int cur = kb & 1;

    f16x8 afrag[4];
#pragma unroll
    for (int rf = 0; rf < 4; ++rf)
      afrag[rf] = *reinterpret_cast<const f16x8*>(&Zlds[cur][(rf * 16 + fr) * BK + fg * 8]);

    float4 va, vb;
    if (kb + 1 < NK) {  // z k+1 issued BEFORE B k+1 so cvt's auto-wait leaves B in flight
      va = *reinterpret_cast<const float4*>(zsrc + (kb + 1) * BK);
      vb = *reinterpret_cast<const float4*>(zsrc + (kb + 1) * BK + 4);
    }

#pragma unroll
    for (int rf = 0; rf < 4; ++rf)
#pragma unroll
      for (int cf = 0; cf < 8; ++cf)
        acc[rf][cf] = __builtin_amdgcn_mfma_f32_16x16x32_f16(afrag[rf], bfr[cf],
                                                             acc[rf][cf], 0, 0, 0);

    if (kb + 1 < NK) {
      // B k+1 into same regs (WAR vs MFMA handled by issue order + HW interlock);
      // stays in flight across the barrier below.
#pragma unroll
      for (int cf = 0; cf < 8; ++cf) bfr[cf] = pB[cf * 512 + (kb + 1) * 4];
      f16x8 h = cvt8(va, vb, zsq);
      *reinterpret_cast<f16x8*>(&Zlds[cur ^ 1][srow * BK + sg * 8]) = h;
      // barrier waits DS only (z tile); vmcnt (B k+1) NOT drained
      asm volatile("s_waitcnt lgkmcnt(0)" ::: "memory");
      __builtin_amdgcn_s_barrier();
    }
  }

  // z row sums-of-squares: combine the 4 staging lanes of each row
  zsq += __shfl_xor(zsq, 1, 64);
  zsq += __shfl_xor(zsq, 2, 64);
  if (sg == 0) zsqs[srow] = zsq;
  __syncthreads();

  // epilogue: sq = z2 + p2 - 2*dot, clamp, row/col mins (sqrt deferred: monotonic)
  float p2l[8];
#pragma unroll
  for (int cf = 0; cf < 8; ++cf) p2l[cf] = p2g[wid * 128 + cf * 16 + fr];
  float zl[4][4];
#pragma unroll
  for (int rf = 0; rf < 4; ++rf)
#pragma unroll
    for (int r = 0; r < 4; ++r) zl[rf][r] = zsqs[rf * 16 + fg * 4 + r];

  float rowm[4][4], colm[8];
#pragma unroll
  for (int rf = 0; rf < 4; ++rf)
#pragma unroll
    for (int r = 0; r < 4; ++r) rowm[rf][r] = 3.4e38f;
#pragma unroll
  for (int cf = 0; cf < 8; ++cf) colm[cf] = 3.4e38f;

#pragma unroll
  for (int rf = 0; rf < 4; ++rf)
#pragma unroll
    for (int cf = 0; cf < 8; ++cf) {
      f32x4 a = acc[rf][cf];
#pragma unroll
      for (int r = 0; r < 4; ++r) {
        float sq = fmaxf(zl[rf][r] + p2l[cf] - 2.f * a[r], EPSQ);
        rowm[rf][r] = fminf(rowm[rf][r], sq);
        colm[cf]    = fminf(colm[cf], sq);
      }
    }

  // row-min across the 16 lanes sharing a row (fr dimension)
#pragma unroll
  for (int m = 1; m <= 8; m <<= 1)
#pragma unroll
    for (int rf = 0; rf < 4; ++rf)
#pragma unroll
      for (int r = 0; r < 4; ++r)
        rowm[rf][r] = fminf(rowm[rf][r], __shfl_xor(rowm[rf][r], m, 64));
  if (fr == 0)
#pragma unroll
    for (int rf = 0; rf < 4; ++rf)
#pragma unroll
      for (int r = 0; r < 4; ++r)
        rowmin_s[wid][rf * 16 + fg * 4 + r] = rowm[rf][r];

  // col-min across the 4 k-groups (fg dimension); each wave owns distinct cols
#pragma unroll
  for (int m = 16; m <= 32; m <<= 1)
#pragma unroll
    for (int cf = 0; cf < 8; ++cf)
      colm[cf] = fminf(colm[cf], __shfl_xor(colm[cf], m, 64));
  if (fg == 0)
#pragma unroll
    for (int cf = 0; cf < 8; ++cf)
      colpart[(size_t)(wid * 128 + cf * 16 + fr) * GRID_MAIN + bid] = colm[cf];  // transposed
  __syncthreads();

  if (t < BM) {  // wave 0 fully active -> shfl safe
    float m = fminf(fminf(rowmin_s[0][t], rowmin_s[1][t]),
                    fminf(rowmin_s[2][t], rowmin_s[3][t]));
    float d = sqrtf(m);
#pragma unroll
    for (int mm = 1; mm < 64; mm <<= 1) d += __shfl_xor(d, mm, 64);
    if (t == 0) rowpart[bid] = d;
  }
}

// ---------------- parallel col-min tree: one block per proto column (coalesced) ----------------
__global__ __launch_bounds__(256) void reduce_cols_k(const float* __restrict__ colpart,
                                                     float* __restrict__ fmin_sq) {
  const int p = blockIdx.x;           // 512 blocks
  const int t = threadIdx.x;          // 256 threads
  const float* row = colpart + (size_t)p * GRID_MAIN;
  float m = 3.4e38f;
#pragma unroll
  for (int j = 0; j < 4; ++j)
    m = fminf(m, row[j * 256 + t]);   // contiguous per wave
#pragma unroll
  for (int mm = 1; mm < 64; mm <<= 1) m = fminf(m, __shfl_xor(m, mm, 64));
  __shared__ float red[4];
  if ((t & 63) == 0) red[t >> 6] = m;
  __syncthreads();
  if (t == 0)
    fmin_sq[p] = fminf(fminf(red[0], red[1]), fminf(red[2], red[3]));
}

// ---------------- finalize: 512 col-mins + 1024 row partial sums -> scalar ----------------
__global__ __launch_bounds__(512) void finalize_k(const float* __restrict__ fmin_sq,
                                                  const float* __restrict__ rowpart,
                                                  float* __restrict__ out) {
  const int t = threadIdx.x, lane = t & 63, wid = t >> 6;
  float fs = sqrtf(fmin_sq[t]);                 // t < 512
  float ps = rowpart[t] + rowpart[t + 512];     // 1024 entries
#pragma unroll
  for (int mm = 1; mm < 64; mm <<= 1) {
    fs += __shfl_xor(fs, mm, 64);
    ps += __shfl_xor(ps, mm, 64);
  }
  __shared__ float red[2][8];
  if (lane == 0) { red[0][wid] = fs; red[1][wid] = ps; }
  __syncthreads();
  if (t == 0) {
    float F = 0.f, P = 0.f;
#pragma unroll
    for (int w = 0; w < 8; ++w) { F += red[0][w]; P += red[1][w]; }
    out[0] = 0.05f * (P / (float)NTOT) + 0.05f * (F / (float)PTOT);
  }
}

extern "C" void kernel_launch(void* const* d_in, const int* in_sizes, int n_in,
                              void* d_out, int out_size, void* d_ws, size_t ws_size,
                              hipStream_t stream) {
  const float* z      = (const float*)d_in[0];  // [65536,256] f32
  const float* protos = (const float*)d_in[1];  // [512,256] f32
  float* out = (float*)d_out;                   // scalar f32

  char* ws = (char*)d_ws;                       // needs ~2.27 MB
  _Float16* protosH = (_Float16*)ws;
  float* p2      = (float*)(ws + WS_P2);
  float* colpart = (float*)(ws + WS_COLPART);
  float* rowpart = (float*)(ws + WS_ROWPART);
  float* fmin_sq = (float*)(ws + WS_FMINSQ);

  proto_prep_k<<<PTOT, 64, 0, stream>>>(protos, protosH, p2);
  pdist_main_k<<<GRID_MAIN, 256, 0, stream>>>(z, protosH, p2, colpart, rowpart);
  reduce_cols_k<<<PTOT, 256, 0, stream>>>(colpart, fmin_sq);
  finalize_k<<<1, 512, 0, stream>>>(fmin_sq, rowpart, out);
}

// Round 10
// 123.332 us; speedup vs baseline: 1.1825x; 1.1825x over previous
//
#include <hip/hip_runtime.h>

// N=65536, P=512, D=256, fp32 in, fp32 scalar out
#define NTOT 65536
#define PTOT 512
#define DTOT 256
#define EPSQ 1e-12f

typedef _Float16 f16x8 __attribute__((ext_vector_type(8)));
typedef _Float16 f16x4 __attribute__((ext_vector_type(4)));
typedef float    f32x4 __attribute__((ext_vector_type(4)));

// ---- ws layout (bytes) ----
// protosR : 256 KB fragment-major f16  [half][kk][cl][lane]*16B
// p2      : 512 f32
// colmin  : 512 u32 (float bits, atomicMin)
// rowsum  : 2048 f32 (256 blocks x 8 waves)
#define WS_P2     262144
#define WS_COLMIN 264192
#define WS_ROWSUM 266240

__device__ __forceinline__ void gload_lds16(const void* g, void* l) {
  __builtin_amdgcn_global_load_lds((const __attribute__((address_space(1))) void*)g,
                                   (__attribute__((address_space(3))) void*)l,
                                   16, 0, 0);
}

__device__ __forceinline__ f16x8 cvt8(const float4 a, const float4 b, float& zsq) {
  f16x8 h;
  h[0] = (_Float16)a.x; h[1] = (_Float16)a.y; h[2] = (_Float16)a.z; h[3] = (_Float16)a.w;
  h[4] = (_Float16)b.x; h[5] = (_Float16)b.y; h[6] = (_Float16)b.z; h[7] = (_Float16)b.w;
#pragma unroll
  for (int i = 0; i < 8; ++i) { float f = (float)h[i]; zsq = fmaf(f, f, zsq); }
  return h;
}

// ---------------- prep: p2 + fragment-major reorder + colmin init ----------------
// One block per proto p. protosR[((h*128 + kk*16 + cl)*64 + fg*16 + fr)*8 f16]
//   = protos[p = h*256 + cl*16 + fr][kk*32 + fg*8 .. +8]  (f16)
__global__ __launch_bounds__(64) void prep_k(const float* __restrict__ protos,
                                             _Float16* __restrict__ protosR,
                                             float* __restrict__ p2,
                                             unsigned* __restrict__ colmin) {
  const int p = blockIdx.x;   // 512
  const int l = threadIdx.x;  // 64
  // p2 from f16-rounded values
  const float4 v = *reinterpret_cast<const float4*>(protos + (size_t)p * DTOT + l * 4);
  float s = 0.f;
#pragma unroll
  for (int i = 0; i < 4; ++i) {
    float f = (float)(_Float16)(((const float*)&v)[i]);
    s = fmaf(f, f, s);
  }
#pragma unroll
  for (int m = 1; m < 64; m <<= 1) s += __shfl_xor(s, m, 64);
  if (l == 0) { p2[p] = s; colmin[p] = 0x7F7FFFFFu; }
  // reorder: threads 0..31 handle (kk, fg)
  if (l < 32) {
    const int kk = l >> 2, fg = l & 3;
    const float4 a = *reinterpret_cast<const float4*>(protos + (size_t)p * DTOT + kk * 32 + fg * 8);
    const float4 b = *reinterpret_cast<const float4*>(protos + (size_t)p * DTOT + kk * 32 + fg * 8 + 4);
    float dummy = 0.f;
    f16x8 h = cvt8(a, b, dummy);
    const int hh = p >> 8, cl = (p >> 4) & 15, fr = p & 15;
    const size_t unit = ((size_t)(hh * 128 + kk * 16 + cl) * 64 + fg * 16 + fr);
    *reinterpret_cast<f16x8*>(protosR + unit * 8) = h;
  }
}

// ---------------- main: 256 blocks x 8 waves; K fully in regs; no k-loop barriers ----
__global__ __launch_bounds__(512, 2) void pdist_main_k(const float* __restrict__ z,
                                                       const _Float16* __restrict__ protosR,
                                                       const float* __restrict__ p2g,
                                                       unsigned* __restrict__ colmin,
                                                       float* __restrict__ rowsum) {
  __shared__ _Float16 Bl[PTOT / 2 * DTOT];  // 128 KB: one 256-col half, frag-major
  __shared__ float colmin_s[8][PTOT];       // 16 KB
  __shared__ float p2s[PTOT];               // 2 KB
  __shared__ float zqs[8][32];              // 1 KB   -> total 147 KB

  const int t    = threadIdx.x;
  const int lane = t & 63;
  const int wid  = t >> 6;        // 0..7
  const int fr   = lane & 15;
  const int fg   = lane >> 4;
  const int bid  = blockIdx.x;
  const int rowbase = bid * 256 + wid * 32;

  // ---- issue all A loads (z fp32, 32B per (rf,kk)) ----
  float4 a4[2][8][2];
#pragma unroll
  for (int rf = 0; rf < 2; ++rf)
#pragma unroll
    for (int kk = 0; kk < 8; ++kk) {
      const float* src = z + (size_t)(rowbase + rf * 16 + fr) * DTOT + kk * 32 + fg * 8;
      a4[rf][kk][0] = *reinterpret_cast<const float4*>(src);
      a4[rf][kk][1] = *reinterpret_cast<const float4*>(src + 4);
    }

  // ---- stage half 0 (linear global_load_lds; prep did the swizzle) ----
  {
    const char* src = (const char*)protosR + (size_t)(wid * 16) * 1024 + lane * 16;
    char* dst = (char*)Bl + (size_t)(wid * 16) * 1024;
#pragma unroll
    for (int u = 0; u < 16; ++u) gload_lds16(src + u * 1024, dst + u * 1024);
  }

  p2s[t] = p2g[t];  // t < 512 == PTOT

  // ---- cvt A to f16 + per-lane zsq ----
  f16x8 af[2][8];
  float zq0 = 0.f, zq1 = 0.f;
#pragma unroll
  for (int kk = 0; kk < 8; ++kk) af[0][kk] = cvt8(a4[0][kk][0], a4[0][kk][1], zq0);
#pragma unroll
  for (int kk = 0; kk < 8; ++kk) af[1][kk] = cvt8(a4[1][kk][0], a4[1][kk][1], zq1);
  // sum k-slices across fg lanes
  zq0 += __shfl_xor(zq0, 16, 64); zq0 += __shfl_xor(zq0, 32, 64);
  zq1 += __shfl_xor(zq1, 16, 64); zq1 += __shfl_xor(zq1, 32, 64);
  if (fg == 0) { zqs[wid][fr] = zq0; zqs[wid][16 + fr] = zq1; }

  __syncthreads();  // barrier 1: half0 staged, p2s/zqs visible

  float zl[2][4];
#pragma unroll
  for (int rf = 0; rf < 2; ++rf)
#pragma unroll
    for (int r = 0; r < 4; ++r) zl[rf][r] = zqs[wid][rf * 16 + fg * 4 + r];

  float rowm[2][4];
#pragma unroll
  for (int rf = 0; rf < 2; ++rf)
#pragma unroll
    for (int r = 0; r < 4; ++r) rowm[rf][r] = 3.4e38f;

#pragma unroll
  for (int h = 0; h < 2; ++h) {
    if (h) {
      __syncthreads();  // all waves done reading half0
      const char* src = (const char*)protosR + 131072 + (size_t)(wid * 16) * 1024 + lane * 16;
      char* dst = (char*)Bl + (size_t)(wid * 16) * 1024;
#pragma unroll
      for (int u = 0; u < 16; ++u) gload_lds16(src + u * 1024, dst + u * 1024);
      __syncthreads();  // half1 staged
    }
#pragma unroll
    for (int c = 0; c < 4; ++c) {
      const int colbase = h * 256 + c * 64;
      f32x4 acc[2][4];
#pragma unroll
      for (int rf = 0; rf < 2; ++rf)
#pragma unroll
        for (int cf = 0; cf < 4; ++cf) acc[rf][cf] = (f32x4)0.f;

#pragma unroll
      for (int kk = 0; kk < 8; ++kk) {
        f16x8 bq[4];
#pragma unroll
        for (int cf = 0; cf < 4; ++cf)
          bq[cf] = *reinterpret_cast<const f16x8*>(
              &Bl[((kk * 16 + c * 4 + cf) * 64 + lane) * 8]);
#pragma unroll
        for (int rf = 0; rf < 2; ++rf)
#pragma unroll
          for (int cf = 0; cf < 4; ++cf)
            acc[rf][cf] = __builtin_amdgcn_mfma_f32_16x16x32_f16(af[rf][kk], bq[cf],
                                                                 acc[rf][cf], 0, 0, 0);
      }

      // chunk epilogue: fold mins (sq split: row needs p2-2dot, col needs zl-2dot)
      float p2l[4], colm[4];
#pragma unroll
      for (int cf = 0; cf < 4; ++cf) {
        p2l[cf]  = p2s[colbase + cf * 16 + fr];
        colm[cf] = 3.4e38f;
      }
#pragma unroll
      for (int rf = 0; rf < 2; ++rf)
#pragma unroll
        for (int cf = 0; cf < 4; ++cf) {
          f32x4 a = acc[rf][cf];
#pragma unroll
          for (int r = 0; r < 4; ++r) {
            const float d2 = -2.f * a[r];
            rowm[rf][r] = fminf(rowm[rf][r], p2l[cf] + d2);
            colm[cf]    = fminf(colm[cf],    zl[rf][r] + d2);
          }
        }
#pragma unroll
      for (int cf = 0; cf < 4; ++cf) {
        colm[cf] = fminf(colm[cf], __shfl_xor(colm[cf], 16, 64));
        colm[cf] = fminf(colm[cf], __shfl_xor(colm[cf], 32, 64));
      }
      if (fg == 0)
#pragma unroll
        for (int cf = 0; cf < 4; ++cf)
          colmin_s[wid][colbase + cf * 16 + fr] = colm[cf] + p2l[cf];
    }
  }

  // ---- row mins -> sqrt -> wave sum ----
#pragma unroll
  for (int rf = 0; rf < 2; ++rf)
#pragma unroll
    for (int r = 0; r < 4; ++r) {
      rowm[rf][r] += zl[rf][r];
#pragma unroll
      for (int m = 1; m <= 8; m <<= 1)
        rowm[rf][r] = fminf(rowm[rf][r], __shfl_xor(rowm[rf][r], m, 64));
    }
  float rsum = 0.f;
  if (fr == 0) {
#pragma unroll
    for (int rf = 0; rf < 2; ++rf)
#pragma unroll
      for (int r = 0; r < 4; ++r) rsum += sqrtf(fmaxf(rowm[rf][r], EPSQ));
  }
#pragma unroll
  for (int m = 1; m < 64; m <<= 1) rsum += __shfl_xor(rsum, m, 64);
  if (lane == 0) rowsum[bid * 8 + wid] = rsum;

  __syncthreads();  // colmin_s complete
  {
    float cm = colmin_s[0][t];
#pragma unroll
    for (int w = 1; w < 8; ++w) cm = fminf(cm, colmin_s[w][t]);
    atomicMin(&colmin[t], __float_as_uint(cm));  // sq >= ~hundreds here; uint-min safe
  }
}

// ---------------- finalize: 512 col-mins + 2048 row sums -> scalar ----------------
__global__ __launch_bounds__(512) void finalize_k(const unsigned* __restrict__ colmin,
                                                  const float* __restrict__ rowsum,
                                                  float* __restrict__ out) {
  const int t = threadIdx.x, lane = t & 63, wid = t >> 6;
  float fs = sqrtf(fmaxf(__uint_as_float(colmin[t]), EPSQ));
  const float4 rv = *reinterpret_cast<const float4*>(rowsum + t * 4);
  float ps = rv.x + rv.y + rv.z + rv.w;
#pragma unroll
  for (int m = 1; m < 64; m <<= 1) {
    fs += __shfl_xor(fs, m, 64);
    ps += __shfl_xor(ps, m, 64);
  }
  __shared__ float red[2][8];
  if (lane == 0) { red[0][wid] = fs; red[1][wid] = ps; }
  __syncthreads();
  if (t == 0) {
    float F = 0.f, P = 0.f;
#pragma unroll
    for (int w = 0; w < 8; ++w) { F += red[0][w]; P += red[1][w]; }
    out[0] = 0.05f * (P / (float)NTOT) + 0.05f * (F / (float)PTOT);
  }
}

extern "C" void kernel_launch(void* const* d_in, const int* in_sizes, int n_in,
                              void* d_out, int out_size, void* d_ws, size_t ws_size,
                              hipStream_t stream) {
  const float* z      = (const float*)d_in[0];  // [65536,256] f32
  const float* protos = (const float*)d_in[1];  // [512,256] f32
  float* out = (float*)d_out;                   // scalar f32

  char* ws = (char*)d_ws;                       // ~274 KB used
  _Float16* protosR = (_Float16*)ws;
  float*    p2      = (float*)(ws + WS_P2);
  unsigned* colmin  = (unsigned*)(ws + WS_COLMIN);
  float*    rowsum  = (float*)(ws + WS_ROWSUM);

  prep_k<<<PTOT, 64, 0, stream>>>(protos, protosR, p2, colmin);
  pdist_main_k<<<NTOT / 256, 512, 0, stream>>>(z, protosR, p2, colmin, rowsum);
  finalize_k<<<1, 512, 0, stream>>>(colmin, rowsum, out);
}